// Round 2
// baseline (641.297 us; speedup 1.0000x reference)
//
#include <hip/hip_runtime.h>
#include <cstdint>

#define IMG_H 512
#define IMG_W 512
#define ROW_BYTES (IMG_W * 4)
#define NPLANES 48                  // 16 batch * 3 channels
#define PLANE_SZ (IMG_H * IMG_W)
#define N_ELEM (NPLANES * PLANE_SZ) // 12,582,912

#define TILE_W 48
#define TILE_H 32
#define GX 11
#define GY 16
#define NBLOCKS (GX * GY * NPLANES) // 8448
#define NSLOTS 8

#define SSIM_C1 1e-4f
#define SSIM_C2 9e-4f

// CK-style raw buffer load: OOB (row<0, row>=H via soffset wrap; bad col via
// huge voffset) returns 0.0f in hardware = free 'SAME' zero padding.
typedef int rsrc_t __attribute__((ext_vector_type(4)));
__device__ float
llvm_amdgcn_raw_buffer_load_fp32(rsrc_t srsrc, int voffset, int soffset,
                                 int glc_slc) __asm("llvm.amdgcn.raw.buffer.load.f32");

__device__ inline rsrc_t make_rsrc(const void* p, int bytes) {
    rsrc_t r;
    r.x = (int)(uint32_t)(uintptr_t)p;       // base lo
    r.y = (int)((uintptr_t)p >> 32);         // base hi, stride=0
    r.z = bytes;                             // num_records (bytes)
    r.w = 0x00020000;                        // raw dword SRD word3
    return r;
}

// Single-kernel SSIM: separable 11x11 Gaussian over 4 channels
// (s=x+y, d=x-y, s^2, d^2), SSIM map, global mean via atomics.
__global__ __launch_bounds__(256) void ssim_kernel(
    const float* __restrict__ img1, const float* __restrict__ img2,
    double* __restrict__ wsum, unsigned* __restrict__ wcnt,
    float* __restrict__ out)
{
    __shared__ float4 vs[TILE_H][65];   // vertical sums, pitch 65 float4
    __shared__ double wred[4];
    __shared__ int lastflag;

    // exact gaussian(ws=11, sigma=1.5) weights (normalized, ~1e-8 abs)
    const float gw[11] = {0.00102838f, 0.00759876f, 0.03600077f, 0.10936069f,
                          0.21300553f, 0.26601172f, 0.21300553f, 0.10936069f,
                          0.03600077f, 0.00759876f, 0.00102838f};

    const int tid  = threadIdx.x;
    const int lane = tid & 63;
    const int wv   = tid >> 6;
    const int ox = blockIdx.x * TILE_W;
    const int oy = blockIdx.y * TILE_H;

    const float* p1 = img1 + (size_t)blockIdx.z * PLANE_SZ;
    const float* p2 = img2 + (size_t)blockIdx.z * PLANE_SZ;
    const rsrc_t rr1 = make_rsrc(p1, PLANE_SZ * 4);
    const rsrc_t rr2 = make_rsrc(p2, PLANE_SZ * 4);

    // ---- vertical pass: wave wv -> output rows [oy+wv*8, +8), lane = halo col
    {
        const int r0 = wv * 8;
        const int srow0 = __builtin_amdgcn_readfirstlane(oy + r0 - 5); // SGPR
        const int gcol = ox + lane - 5;
        // valid col -> byte offset; invalid col -> huge offset -> OOB -> 0
        const int coff = ((unsigned)gcol < (unsigned)IMG_W) ? (gcol * 4) : 0x48000000;

        float4 acc[8];
        #pragma unroll
        for (int o = 0; o < 8; ++o) acc[o] = make_float4(0.f, 0.f, 0.f, 0.f);

        #pragma unroll
        for (int i = 0; i < 18; ++i) {            // input rows srow0 .. srow0+17
            const int soff = (srow0 + i) * ROW_BYTES;  // SGPR soffset (neg -> OOB)
            const float x = llvm_amdgcn_raw_buffer_load_fp32(rr1, coff, soff, 0);
            const float y = llvm_amdgcn_raw_buffer_load_fp32(rr2, coff, soff, 0);
            const float s = x + y, d = x - y;
            const float s2 = s * s, d2 = d * d;
            #pragma unroll
            for (int o = 0; o < 8; ++o) {
                const int k = i - o;              // tap index (static)
                if (k >= 0 && k <= 10) {
                    const float w = gw[k];
                    acc[o].x = fmaf(w, s,  acc[o].x);
                    acc[o].y = fmaf(w, d,  acc[o].y);
                    acc[o].z = fmaf(w, s2, acc[o].z);
                    acc[o].w = fmaf(w, d2, acc[o].w);
                }
            }
        }
        #pragma unroll
        for (int o = 0; o < 8; ++o) vs[r0 + o][lane] = acc[o];
    }
    __syncthreads();

    // ---- horizontal pass + SSIM: thread -> 1 row x 6 consecutive cols
    float lsum = 0.f;
    {
        const int r  = tid >> 3;
        const int c0 = (tid & 7) * 6;
        float4 m[6];
        #pragma unroll
        for (int j = 0; j < 6; ++j) m[j] = make_float4(0.f, 0.f, 0.f, 0.f);
        #pragma unroll
        for (int t = 0; t < 16; ++t) {
            const float4 v = vs[r][c0 + t];
            #pragma unroll
            for (int j = 0; j < 6; ++j) {
                const int k = t - j;
                if (k >= 0 && k <= 10) {
                    const float w = gw[k];
                    m[j].x = fmaf(w, v.x, m[j].x);
                    m[j].y = fmaf(w, v.y, m[j].y);
                    m[j].z = fmaf(w, v.z, m[j].z);
                    m[j].w = fmaf(w, v.w, m[j].w);
                }
            }
        }
        #pragma unroll
        for (int j = 0; j < 6; ++j) {
            if (ox + c0 + j < IMG_W) {           // clip right-edge partial tile
                const float mus = m[j].x, mud = m[j].y;
                const float es2 = m[j].z, ed2 = m[j].w;
                const float a = mus * mus, b = mud * mud;
                // mu1 = (mus+mud)/2, mu2 = (mus-mud)/2:
                const float num1 = (a - b) * 0.5f + SSIM_C1;            // 2*mu1*mu2 + C1
                const float den1 = (a + b) * 0.5f + SSIM_C1;            // mu1^2+mu2^2 + C1
                const float num2 = (es2 - ed2 - (a - b)) * 0.5f + SSIM_C2; // 2*sigma12 + C2
                const float den2 = (es2 + ed2 - (a + b)) * 0.5f + SSIM_C2; // s1+s2 + C2
                lsum += (num1 * num2) * __builtin_amdgcn_rcpf(den1 * den2);
            }
        }
    }

    // ---- reduce: wave shuffle (fp32) -> LDS (fp64) -> block -> global atomics
    #pragma unroll
    for (int off = 32; off > 0; off >>= 1)
        lsum += __shfl_down(lsum, off, 64);
    if (lane == 0) wred[wv] = (double)lsum;
    __syncthreads();
    if (tid == 0) {
        const double bsum = wred[0] + wred[1] + wred[2] + wred[3];
        const int bid = blockIdx.x + GX * (blockIdx.y + GY * blockIdx.z);
        atomicAdd(&wsum[bid & (NSLOTS - 1)], bsum);
        __threadfence();                          // release: sum before count
        const unsigned old = atomicAdd(wcnt, 1u);
        lastflag = (old == NBLOCKS - 1);
        __threadfence();                          // acquire for slot reads below
    }
    __syncthreads();
    if (lastflag && wv == 0) {                    // last block: fold 8 slots
        double v = (lane < NSLOTS) ? atomicAdd(&wsum[lane], 0.0) : 0.0;
        v += __shfl_down(v, 4, 64);
        v += __shfl_down(v, 2, 64);
        v += __shfl_down(v, 1, 64);
        if (lane == 0) out[0] = (float)(v / (double)N_ELEM);
    }
}

extern "C" void kernel_launch(void* const* d_in, const int* in_sizes, int n_in,
                              void* d_out, int out_size, void* d_ws, size_t ws_size,
                              hipStream_t stream)
{
    const float* img1 = (const float*)d_in[0];
    const float* img2 = (const float*)d_in[1];
    double* wsum   = (double*)d_ws;                       // 8 slots
    unsigned* wcnt = (unsigned*)((char*)d_ws + NSLOTS * 8);
    float* out     = (float*)d_out;

    hipMemsetAsync(d_ws, 0, NSLOTS * 8 + 16, stream);     // zero slots + counter
    dim3 grid(GX, GY, NPLANES);
    ssim_kernel<<<grid, dim3(256), 0, stream>>>(img1, img2, wsum, wcnt, out);
}

// Round 3
// 138.630 us; speedup vs baseline: 4.6260x; 4.6260x over previous
//
#include <hip/hip_runtime.h>
#include <cstdint>

#define IMG_H 512
#define IMG_W 512
#define ROW_BYTES (IMG_W * 4)
#define NPLANES 48                  // 16 batch * 3 channels
#define PLANE_SZ (IMG_H * IMG_W)
#define N_ELEM (NPLANES * PLANE_SZ) // 12,582,912

#define TILE_W 48
#define TILE_H 32
#define GX 11
#define GY 16
#define NBLOCKS (GX * GY * NPLANES) // 8448

#define SSIM_C1 1e-4f
#define SSIM_C2 9e-4f

// CK-style raw buffer load: OOB (row<0 / row>=H via soffset; bad col via huge
// voffset) returns 0.0f in hardware = free 'SAME' zero padding, zero VALU.
typedef int rsrc_t __attribute__((ext_vector_type(4)));
__device__ float
llvm_amdgcn_raw_buffer_load_fp32(rsrc_t srsrc, int voffset, int soffset,
                                 int glc_slc) __asm("llvm.amdgcn.raw.buffer.load.f32");

__device__ inline rsrc_t make_rsrc(const void* p, int bytes) {
    rsrc_t r;
    r.x = (int)(uint32_t)(uintptr_t)p;       // base lo
    r.y = (int)((uintptr_t)p >> 32);         // base hi, stride=0
    r.z = bytes;                             // num_records (bytes)
    r.w = 0x00020000;                        // raw dword SRD word3
    return r;
}

// Tile kernel: separable 11x11 Gaussian over 4 channels
// (s=x+y, d=x-y, s^2, d^2), SSIM map, per-block partial -> plain store.
__global__ __launch_bounds__(256) void ssim_tile_kernel(
    const float* __restrict__ img1, const float* __restrict__ img2,
    double* __restrict__ partials)
{
    __shared__ float4 vs[TILE_H][65];   // vertical sums, pitch 65 float4
    __shared__ double wred[4];

    // exact gaussian(ws=11, sigma=1.5) weights (normalized, ~1e-8 abs)
    const float gw[11] = {0.00102838f, 0.00759876f, 0.03600077f, 0.10936069f,
                          0.21300553f, 0.26601172f, 0.21300553f, 0.10936069f,
                          0.03600077f, 0.00759876f, 0.00102838f};

    const int tid  = threadIdx.x;
    const int lane = tid & 63;
    const int wv   = tid >> 6;
    const int ox = blockIdx.x * TILE_W;
    const int oy = blockIdx.y * TILE_H;

    const float* p1 = img1 + (size_t)blockIdx.z * PLANE_SZ;
    const float* p2 = img2 + (size_t)blockIdx.z * PLANE_SZ;
    const rsrc_t rr1 = make_rsrc(p1, PLANE_SZ * 4);
    const rsrc_t rr2 = make_rsrc(p2, PLANE_SZ * 4);

    // ---- vertical pass: wave wv -> output rows [oy+wv*8, +8), lane = halo col
    {
        const int r0 = wv * 8;
        const int srow0 = __builtin_amdgcn_readfirstlane(oy + r0 - 5); // SGPR
        const int gcol = ox + lane - 5;
        // valid col -> byte offset; invalid col -> huge offset -> OOB -> 0
        const int coff = ((unsigned)gcol < (unsigned)IMG_W) ? (gcol * 4) : 0x48000000;

        float4 acc[8];
        #pragma unroll
        for (int o = 0; o < 8; ++o) acc[o] = make_float4(0.f, 0.f, 0.f, 0.f);

        #pragma unroll
        for (int i = 0; i < 18; ++i) {            // input rows srow0 .. srow0+17
            const int soff = (srow0 + i) * ROW_BYTES;  // SGPR soffset (neg -> OOB)
            const float x = llvm_amdgcn_raw_buffer_load_fp32(rr1, coff, soff, 0);
            const float y = llvm_amdgcn_raw_buffer_load_fp32(rr2, coff, soff, 0);
            const float s = x + y, d = x - y;
            const float s2 = s * s, d2 = d * d;
            #pragma unroll
            for (int o = 0; o < 8; ++o) {
                const int k = i - o;              // tap index (static)
                if (k >= 0 && k <= 10) {
                    const float w = gw[k];
                    acc[o].x = fmaf(w, s,  acc[o].x);
                    acc[o].y = fmaf(w, d,  acc[o].y);
                    acc[o].z = fmaf(w, s2, acc[o].z);
                    acc[o].w = fmaf(w, d2, acc[o].w);
                }
            }
        }
        #pragma unroll
        for (int o = 0; o < 8; ++o) vs[r0 + o][lane] = acc[o];
    }
    __syncthreads();

    // ---- horizontal pass + SSIM: thread -> 1 row x 6 consecutive cols
    float lsum = 0.f;
    {
        const int r  = tid >> 3;
        const int c0 = (tid & 7) * 6;
        float4 m[6];
        #pragma unroll
        for (int j = 0; j < 6; ++j) m[j] = make_float4(0.f, 0.f, 0.f, 0.f);
        #pragma unroll
        for (int t = 0; t < 16; ++t) {
            const float4 v = vs[r][c0 + t];
            #pragma unroll
            for (int j = 0; j < 6; ++j) {
                const int k = t - j;
                if (k >= 0 && k <= 10) {
                    const float w = gw[k];
                    m[j].x = fmaf(w, v.x, m[j].x);
                    m[j].y = fmaf(w, v.y, m[j].y);
                    m[j].z = fmaf(w, v.z, m[j].z);
                    m[j].w = fmaf(w, v.w, m[j].w);
                }
            }
        }
        #pragma unroll
        for (int j = 0; j < 6; ++j) {
            if (ox + c0 + j < IMG_W) {           // clip right-edge partial tile
                const float mus = m[j].x, mud = m[j].y;
                const float es2 = m[j].z, ed2 = m[j].w;
                const float a = mus * mus, b = mud * mud;
                // mu1 = (mus+mud)/2, mu2 = (mus-mud)/2:
                const float num1 = (a - b) * 0.5f + SSIM_C1;               // 2*mu1*mu2 + C1
                const float den1 = (a + b) * 0.5f + SSIM_C1;               // mu1^2+mu2^2 + C1
                const float num2 = (es2 - ed2 - (a - b)) * 0.5f + SSIM_C2; // 2*sigma12 + C2
                const float den2 = (es2 + ed2 - (a + b)) * 0.5f + SSIM_C2; // s1+s2 + C2
                lsum += (num1 * num2) * __builtin_amdgcn_rcpf(den1 * den2);
            }
        }
    }

    // ---- block reduction -> one partial per block, plain store (no atomics)
    #pragma unroll
    for (int off = 32; off > 0; off >>= 1)
        lsum += __shfl_down(lsum, off, 64);
    if (lane == 0) wred[wv] = (double)lsum;
    __syncthreads();
    if (tid == 0) {
        const int bid = blockIdx.x + GX * (blockIdx.y + GY * blockIdx.z);
        partials[bid] = wred[0] + wred[1] + wred[2] + wred[3];
    }
}

// 1 block x 1024 threads: ~8 independent loads per thread, then tree-reduce.
__global__ __launch_bounds__(1024) void ssim_finalize_kernel(
    const double* __restrict__ partials, float* __restrict__ out)
{
    __shared__ double wred[16];
    const int tid  = threadIdx.x;
    const int lane = tid & 63;
    const int wv   = tid >> 6;
    double s = 0.0;
    #pragma unroll
    for (int i = 0; i < 9; ++i) {             // 9*1024 >= 8448, independent loads
        const int idx = tid + i * 1024;
        if (idx < NBLOCKS) s += partials[idx];
    }
    #pragma unroll
    for (int off = 32; off > 0; off >>= 1)
        s += __shfl_down(s, off, 64);
    if (lane == 0) wred[wv] = s;
    __syncthreads();
    if (wv == 0) {
        double v = (lane < 16) ? wred[lane] : 0.0;
        v += __shfl_down(v, 8, 64);
        v += __shfl_down(v, 4, 64);
        v += __shfl_down(v, 2, 64);
        v += __shfl_down(v, 1, 64);
        if (lane == 0) out[0] = (float)(v / (double)N_ELEM);
    }
}

extern "C" void kernel_launch(void* const* d_in, const int* in_sizes, int n_in,
                              void* d_out, int out_size, void* d_ws, size_t ws_size,
                              hipStream_t stream)
{
    const float* img1 = (const float*)d_in[0];
    const float* img2 = (const float*)d_in[1];
    double* partials  = (double*)d_ws;          // 8448 * 8B = 67.6 KB scratch
    float* out        = (float*)d_out;

    dim3 grid(GX, GY, NPLANES);
    ssim_tile_kernel<<<grid, dim3(256), 0, stream>>>(img1, img2, partials);
    ssim_finalize_kernel<<<1, dim3(1024), 0, stream>>>(partials, out);
}

// Round 4
// 136.308 us; speedup vs baseline: 4.7048x; 1.0170x over previous
//
#include <hip/hip_runtime.h>
#include <cstdint>

#define IMG_H 512
#define IMG_W 512
#define ROW_BYTES (IMG_W * 4)
#define NPLANES 48                  // 16 batch * 3 channels
#define PLANE_SZ (IMG_H * IMG_W)
#define N_ELEM (NPLANES * PLANE_SZ) // 12,582,912

#define TILE_W 48
#define TILE_H 32
#define GX 11
#define GY 16
#define NBLOCKS (GX * GY * NPLANES) // 8448
#define VPITCH 59                   // stored halo cols 0..57 (+1 pad)

#define SSIM_C1 1e-4f
#define SSIM_C2 9e-4f

// Raw buffer load: OOB (row<0 / row>=H via soffset; bad col via huge voffset)
// returns 0.0f in hardware = free 'SAME' zero padding, zero bounds VALU.
typedef int rsrc_t __attribute__((ext_vector_type(4)));
__device__ float
llvm_amdgcn_raw_buffer_load_fp32(rsrc_t srsrc, int voffset, int soffset,
                                 int glc_slc) __asm("llvm.amdgcn.raw.buffer.load.f32");

__device__ inline rsrc_t make_rsrc(const void* p, int bytes) {
    rsrc_t r;
    r.x = (int)(uint32_t)(uintptr_t)p;       // base lo
    r.y = (int)((uintptr_t)p >> 32);         // base hi, stride=0
    r.z = bytes;                             // num_records (bytes)
    r.w = 0x00020000;                        // raw dword SRD word3
    return r;
}

// Separable 11x11 Gaussian over 4 channels (s=x+y, d=x-y, s^2, d^2),
// SSIM map, per-block partial. launch_bounds(256,4): VGPR<=128 so the
// 36 vertical loads can ALL be in flight (R3: 52 VGPR -> serialized stalls).
__global__ __launch_bounds__(256, 4) void ssim_tile_kernel(
    const float* __restrict__ img1, const float* __restrict__ img2,
    double* __restrict__ partials)
{
    __shared__ float4 vs[TILE_H][VPITCH]; // 30.2 KB -> 5 blocks/CU
    __shared__ double wred[4];

    // exact gaussian(ws=11, sigma=1.5) weights (normalized, ~1e-8 abs)
    const float gw[11] = {0.00102838f, 0.00759876f, 0.03600077f, 0.10936069f,
                          0.21300553f, 0.26601172f, 0.21300553f, 0.10936069f,
                          0.03600077f, 0.00759876f, 0.00102838f};

    const int tid  = threadIdx.x;
    const int lane = tid & 63;
    const int wv   = tid >> 6;
    const int ox = blockIdx.x * TILE_W;
    const int oy = blockIdx.y * TILE_H;

    const float* p1 = img1 + (size_t)blockIdx.z * PLANE_SZ;
    const float* p2 = img2 + (size_t)blockIdx.z * PLANE_SZ;
    const rsrc_t rr1 = make_rsrc(p1, PLANE_SZ * 4);
    const rsrc_t rr2 = make_rsrc(p2, PLANE_SZ * 4);

    // ---- vertical pass: wave wv -> output rows [oy+wv*8, +8), lane = halo col
    {
        const int r0 = wv * 8;
        const int srow0 = __builtin_amdgcn_readfirstlane(oy + r0 - 5); // SGPR
        const int gcol = ox + lane - 5;
        const int coff = ((unsigned)gcol < (unsigned)IMG_W) ? (gcol * 4) : 0x48000000;

        // Stage 1: issue ALL 36 loads back-to-back (max memory-level parallelism)
        float xs[18], ys[18];
        #pragma unroll
        for (int i = 0; i < 18; ++i) {
            const int soff = (srow0 + i) * ROW_BYTES;  // SGPR soffset
            xs[i] = llvm_amdgcn_raw_buffer_load_fp32(rr1, coff, soff, 0);
            ys[i] = llvm_amdgcn_raw_buffer_load_fp32(rr2, coff, soff, 0);
        }

        // Stage 2: consume
        float4 acc[8];
        #pragma unroll
        for (int o = 0; o < 8; ++o) acc[o] = make_float4(0.f, 0.f, 0.f, 0.f);
        #pragma unroll
        for (int i = 0; i < 18; ++i) {
            const float s = xs[i] + ys[i], d = xs[i] - ys[i];
            const float s2 = s * s, d2 = d * d;
            #pragma unroll
            for (int o = 0; o < 8; ++o) {
                const int k = i - o;              // tap index (static)
                if (k >= 0 && k <= 10) {
                    const float w = gw[k];
                    acc[o].x = fmaf(w, s,  acc[o].x);
                    acc[o].y = fmaf(w, d,  acc[o].y);
                    acc[o].z = fmaf(w, s2, acc[o].z);
                    acc[o].w = fmaf(w, d2, acc[o].w);
                }
            }
        }
        if (lane < 58) {                          // only cols used by horizontal
            #pragma unroll
            for (int o = 0; o < 8; ++o) vs[r0 + o][lane] = acc[o];
        }
    }
    __syncthreads();

    // ---- horizontal pass + SSIM: thread -> 1 row x 6 consecutive cols
    float lsum = 0.f;
    {
        const int r  = tid >> 3;
        const int c0 = (tid & 7) * 6;            // max read col 42+15=57 < 58
        float4 m[6];
        #pragma unroll
        for (int j = 0; j < 6; ++j) m[j] = make_float4(0.f, 0.f, 0.f, 0.f);
        #pragma unroll
        for (int t = 0; t < 16; ++t) {
            const float4 v = vs[r][c0 + t];
            #pragma unroll
            for (int j = 0; j < 6; ++j) {
                const int k = t - j;
                if (k >= 0 && k <= 10) {
                    const float w = gw[k];
                    m[j].x = fmaf(w, v.x, m[j].x);
                    m[j].y = fmaf(w, v.y, m[j].y);
                    m[j].z = fmaf(w, v.z, m[j].z);
                    m[j].w = fmaf(w, v.w, m[j].w);
                }
            }
        }
        #pragma unroll
        for (int j = 0; j < 6; ++j) {
            if (ox + c0 + j < IMG_W) {           // clip right-edge partial tile
                const float mus = m[j].x, mud = m[j].y;
                const float es2 = m[j].z, ed2 = m[j].w;
                const float a = mus * mus, b = mud * mud;
                // mu1 = (mus+mud)/2, mu2 = (mus-mud)/2:
                const float num1 = (a - b) * 0.5f + SSIM_C1;               // 2*mu1*mu2 + C1
                const float den1 = (a + b) * 0.5f + SSIM_C1;               // mu1^2+mu2^2 + C1
                const float num2 = (es2 - ed2 - (a - b)) * 0.5f + SSIM_C2; // 2*sigma12 + C2
                const float den2 = (es2 + ed2 - (a + b)) * 0.5f + SSIM_C2; // s1+s2 + C2
                lsum += (num1 * num2) * __builtin_amdgcn_rcpf(den1 * den2);
            }
        }
    }

    // ---- block reduction -> one partial per block, plain store (no atomics)
    #pragma unroll
    for (int off = 32; off > 0; off >>= 1)
        lsum += __shfl_down(lsum, off, 64);
    if (lane == 0) wred[wv] = (double)lsum;
    __syncthreads();
    if (tid == 0) {
        const int bid = blockIdx.x + GX * (blockIdx.y + GY * blockIdx.z);
        partials[bid] = wred[0] + wred[1] + wred[2] + wred[3];
    }
}

// 1 block x 1024 threads: ~8 independent loads per thread, then tree-reduce.
__global__ __launch_bounds__(1024) void ssim_finalize_kernel(
    const double* __restrict__ partials, float* __restrict__ out)
{
    __shared__ double wred[16];
    const int tid  = threadIdx.x;
    const int lane = tid & 63;
    const int wv   = tid >> 6;
    double s = 0.0;
    #pragma unroll
    for (int i = 0; i < 9; ++i) {
        const int idx = tid + i * 1024;
        if (idx < NBLOCKS) s += partials[idx];
    }
    #pragma unroll
    for (int off = 32; off > 0; off >>= 1)
        s += __shfl_down(s, off, 64);
    if (lane == 0) wred[wv] = s;
    __syncthreads();
    if (wv == 0) {
        double v = (lane < 16) ? wred[lane] : 0.0;
        v += __shfl_down(v, 8, 64);
        v += __shfl_down(v, 4, 64);
        v += __shfl_down(v, 2, 64);
        v += __shfl_down(v, 1, 64);
        if (lane == 0) out[0] = (float)(v / (double)N_ELEM);
    }
}

extern "C" void kernel_launch(void* const* d_in, const int* in_sizes, int n_in,
                              void* d_out, int out_size, void* d_ws, size_t ws_size,
                              hipStream_t stream)
{
    const float* img1 = (const float*)d_in[0];
    const float* img2 = (const float*)d_in[1];
    double* partials  = (double*)d_ws;          // 8448 * 8B = 67.6 KB scratch
    float* out        = (float*)d_out;

    dim3 grid(GX, GY, NPLANES);
    ssim_tile_kernel<<<grid, dim3(256), 0, stream>>>(img1, img2, partials);
    ssim_finalize_kernel<<<1, dim3(1024), 0, stream>>>(partials, out);
}